// Round 18
// baseline (106.668 us; speedup 1.0000x reference)
//
#include <hip/hip_runtime.h>

// ---------- types ----------
typedef __attribute__((ext_vector_type(8))) short short8;     // 8 bf16 (4 VGPRs)
typedef __attribute__((ext_vector_type(4))) float floatx4;    // MFMA C/D
typedef __attribute__((ext_vector_type(4))) unsigned int uintx4;

// ---------- fp32 -> packed bf16x2 (RNE) ----------
#if __has_builtin(__builtin_amdgcn_cvt_pk_bf16_f32)
typedef __attribute__((ext_vector_type(2))) __bf16 bf16x2;
__device__ __forceinline__ unsigned int pk_bf16(float a, float b) {
  bf16x2 v = __builtin_amdgcn_cvt_pk_bf16_f32(a, b);
  return __builtin_bit_cast(unsigned int, v);
}
#else
__device__ __forceinline__ unsigned int bf16_1(float f) {
  unsigned int u = __builtin_bit_cast(unsigned int, f);
  return (u + 0x7fffu + ((u >> 16) & 1u)) >> 16;
}
__device__ __forceinline__ unsigned int pk_bf16(float a, float b) {
  return bf16_1(a) | (bf16_1(b) << 16);
}
#endif

// Fragment conventions (verified rounds 0-17, absmax 3.9e-3):
//   A-frag (16x16x32): lane(ln,quad) holds A[m=ln][k=quad*8+j], j=0..7
//   B-frag:            lane(ln,quad) holds B[n=ln][k=quad*8+j]  (B[k][n]=W[c][r][k], n=r*8+c)
//   C/D:               col=ln, row=quad*4+reg
// Bprep frag id: Fb = ((mod*8 + h)*24 + ks)*4 + nt, n16 = h*4+nt; frag = 64 lanes x 16B.
//
// LEDGER (do not revisit without new evidence):
// * STORE GEOMETRY LOAD-BEARING: 16 consecutive dwords per 16-lane group
//   x 4 rows/instr = 1.0x writes. Anything else 1.5-3.0x.
// * NT STORES: 3x writes (r3). NT LOADS: kill L3 residency (r15 bench).
// * PERMUTED-B + direct stores: silent transpose (r6).
// * REG-SPILL SIGNATURE: WRITE balloon + 2.4x dur (r7).
// * OCCUPANCY 43->76%: zero (r10). PREFETCH 2->3: zero (r11).
//   K-STAGGER: zero (r13). VALU DIET: zero (r14). SC1: null instrument (r16).
// * CONFIRMED (r15, NT isolation): X streaming evicts B from per-XCD L2 ->
//   B served from L3 -> ~25% cost. No flag gives L2-noalloc + L3-alloc.
// * REGISTER-RESIDENT B (r17): B traffic removed but 1 blk/CU serial-stage
//   + 2x X taxes net +15 us. Traffic cuts must avoid occupancy/X taxes.
// ROUND-18: K-SPLIT WAVE PAIRS. 1024 thr / 16 waves = 8 col-groups x 2
// K-halves; wave (cg,kh) computes a PARTIAL sum over 12 of 24 K-steps,
// reading 48 KB of B (not 96). Block B reads 768->384 KB; kernel B
// traffic 1.18 GB -> 590 MB. X read once; MFMA & total LDS-A unchanged.
// Recombine: kh=1 waves write acc to a 64 KB LDS area, barrier, kh=0
// waves add + run the proven epilogue. Cost: 1 blk/CU serial-stage tax.

// ============================================================
// Prepass W: [8][64][768] fp32 -> bf16 B-fragments; bias permuted to n-order.
// ============================================================
__global__ __launch_bounds__(256) void prep_w(
    const float* __restrict__ Wi, const float* __restrict__ Wc, const float* __restrict__ Wd,
    const float* __restrict__ bi, const float* __restrict__ bc, const float* __restrict__ bd,
    uintx4* __restrict__ Bprep, float* __restrict__ biasPrep) {
  const int t = blockIdx.x * 256 + threadIdx.x;  // 0 .. 147455
  const int l = t & 63;
  const int frag = t >> 6;             // 0 .. 2303
  const int nt = frag & 3;
  const int q = frag >> 2;
  const int ks = q % 24;
  const int q2 = q / 24;
  const int h = q2 & 7;
  const int mod = q2 >> 3;
  const int n16 = h * 4 + nt;
  const float* __restrict__ W = (mod == 0) ? Wi : ((mod == 1) ? Wc : Wd);

  const int n = n16 * 16 + (l & 15);
  const int r = n >> 3;
  const int c = n & 7;
  const int i0 = ks * 32 + (l >> 4) * 8;
  const float* src = W + (size_t)(c * 64 + r) * 768 + i0;
  floatx4 f0 = *(const floatx4*)(src);
  floatx4 f1 = *(const floatx4*)(src + 4);
  uintx4 p;
  p.x = pk_bf16(f0.x, f0.y);
  p.y = pk_bf16(f0.z, f0.w);
  p.z = pk_bf16(f1.x, f1.y);
  p.w = pk_bf16(f1.z, f1.w);
  Bprep[(size_t)frag * 64 + l] = p;

  if (t < 1536) {
    const int m2 = t >> 9;
    const int nn = t & 511;
    const float* bb = (m2 == 0) ? bi : ((m2 == 1) ? bc : bd);
    biasPrep[t] = bb[(nn & 7) * 64 + (nn >> 3)];
  }
}

// ============================================================
// Fused GEMM + squash, K-SPLIT wave pairs.
//   Block: 1024 thr / 16 waves = 8 col-groups (cg, 64 cols) x 2 K-halves.
//   Wave (cg,kh): acc[2][4] partial over ks in [kh*12, kh*12+12).
//   A (32x768) staged once as bf16 frags in 48 KB LDS (slot-XOR);
//   2-deep register prefetch, fully unrolled 12-step K-loop;
//   64 KB LDS exchange recombines K-halves; kh=0 waves do the epilogue
//   (shuffle-squash + rsq/rcp + imm-offset proven 1.0x stores).
//   launch_bounds(1024,4): ~108 regs -> 16 waves = 1 block/CU.
//   Grid 1536 = 3 mods x 512 m-tiles (XCD swizzle 8x192).
// ============================================================
#define LOADA(aa, kk) /* kk = LOCAL step 0..11; global ks = kh*12+kk */      \
  {                                                                          \
    _Pragma("unroll") for (int mt = 0; mt < 2; ++mt)                         \
        aa[mt] = Afr[((khb + (kk)) * 2 + mt) * 64 +                          \
                     ((ln ^ (((khb + (kk)) * 4 + quad) & 15)) +              \
                      (quad << 4))];                                         \
  }

#define LOADB(bb, kk)                                                        \
  {                                                                          \
    _Pragma("unroll") for (int n2 = 0; n2 < 4; ++n2)                         \
        bb[n2] = bbase[((kk) * 4 + n2) * 64];                                \
  }

#define COMP(aa, bb)                                                     \
  {                                                                      \
    _Pragma("unroll") for (int mt = 0; mt < 2; ++mt)                     \
    {                                                                    \
      short8 af = __builtin_bit_cast(short8, aa[mt]);                    \
      _Pragma("unroll") for (int n2 = 0; n2 < 4; ++n2)                   \
          acc[mt][n2] = __builtin_amdgcn_mfma_f32_16x16x32_bf16(         \
              af, __builtin_bit_cast(short8, bb[n2]), acc[mt][n2], 0, 0, \
              0);                                                        \
    }                                                                    \
  }

__global__ __launch_bounds__(1024, 4) void caps_fused(
    const float* __restrict__ x0, const float* __restrict__ x1, const float* __restrict__ x2,
    const uintx4* __restrict__ Bprep, const float* __restrict__ biasPrep,
    float* __restrict__ out) {
  __shared__ unsigned long long As64[48 * 128];  // 48 KB: A-frags
  __shared__ floatx4 Ex[8 * 8 * 64];             // 64 KB: K-half exchange

  const int tid = threadIdx.x;
  // XCD-chunk swizzle: 1536 = 8 XCDs x 192 contiguous blocks (bijective).
  const int bx0 = blockIdx.x;
  const int bx = (bx0 & 7) * 192 + (bx0 >> 3);
  const int mod = bx >> 9;           // 1536 = 3 x 512
  const int bm = bx & 511;           // m-tile (32 rows)
  const float* __restrict__ X = (mod == 0) ? x0 : ((mod == 1) ? x1 : x2);

  // ---- one-shot staging: 32 rows x 768 cols fp32, coalesced, 1024 thr ----
  const float* src = X + (size_t)bm * 32 * 768;
#pragma unroll
  for (int i = 0; i < 6; ++i) {
    const int idx = i * 4096 + tid * 4;          // flat float index in tile
    floatx4 f = *(const floatx4*)(src + idx);
    const int m = (unsigned)idx / 768u;
    const int k = idx - m * 768;
    const int ks = k >> 5;
    const int kk = k & 31;
    const int qk = kk >> 3;                      // quad of k
    const int jh = (kk >> 2) & 1;                // which 8-byte half
    const int mt = m >> 4;
    const int lnn = m & 15;
    const int p = (ks * 4 + qk) & 15;            // slot-XOR spread
    const int slot = (lnn ^ p) + (qk << 4);
    unsigned long long w =
        ((unsigned long long)pk_bf16(f.z, f.w) << 32) | pk_bf16(f.x, f.y);
    As64[(((ks * 2 + mt) * 64 + slot) << 1) + jh] = w;
  }
  __syncthreads();

  const int lane = tid & 63;
  const int ln = lane & 15;
  const int quad = lane >> 4;
  const int wv = tid >> 6;           // 0..15
  const int cg = wv & 7;             // col-group: n16 = cg*4 .. cg*4+3
  const int kh = wv >> 3;            // K-half
  const int khb = kh * 12;           // global ks base

  const uintx4* Afr = (const uintx4*)As64;
  const uintx4* bbase =
      Bprep + (size_t)(mod * 8 + cg) * (96 * 64) + khb * 4 * 64 + lane;

  floatx4 acc[2][4] = {};
  uintx4 a0[2], a1[2], b0[4], b1[4];

  // ---- 12-step K-loop (this wave's K-half), 2-deep, fully unrolled ----
  LOADA(a0, 0); LOADB(b0, 0);
#pragma unroll
  for (int j = 0; j < 6; ++j) {
    const int s = 2 * j;
    LOADA(a1, s + 1); LOADB(b1, s + 1);
    COMP(a0, b0);
    if (j != 5) { LOADA(a0, s + 2); LOADB(b0, s + 2); }
    COMP(a1, b1);
  }

  // ---- K-half recombine through LDS ----
  if (kh == 1) {
#pragma unroll
    for (int mt = 0; mt < 2; ++mt)
#pragma unroll
      for (int n2 = 0; n2 < 4; ++n2)
        Ex[((mt * 4 + n2) * 8 + cg) * 64 + lane] = acc[mt][n2];
  }
  __syncthreads();
  if (kh == 0) {
#pragma unroll
    for (int mt = 0; mt < 2; ++mt)
#pragma unroll
      for (int n2 = 0; n2 < 4; ++n2) {
        floatx4 o = Ex[((mt * 4 + n2) * 8 + cg) * 64 + lane];
        acc[mt][n2].x += o.x; acc[mt][n2].y += o.y;
        acc[mt][n2].z += o.z; acc[mt][n2].w += o.w;
      }

    // ---- epilogue: bias + squash + imm-offset stores (1.0x geometry) ----
    const int col0 = mod * 512 + cg * 64 + ln;
    float bias[4];
#pragma unroll
    for (int n2 = 0; n2 < 4; ++n2) bias[n2] = biasPrep[col0 + n2 * 16];

#pragma unroll
    for (int mt = 0; mt < 2; ++mt) {
      float* opm = out + (size_t)(bm * 32 + mt * 16 + quad * 4) * 1536 + col0;
#pragma unroll
      for (int jj = 0; jj < 4; ++jj) {
        float* opj = opm + jj * 1536;  // one 64-bit add per 4 stores
#pragma unroll
        for (int n2 = 0; n2 < 4; ++n2) {
          float u = acc[mt][n2][jj] + bias[n2];
          float s = u * u;
          s += __shfl_xor(s, 1);
          s += __shfl_xor(s, 2);
          s += __shfl_xor(s, 4);
#if __has_builtin(__builtin_amdgcn_rsqf) && __has_builtin(__builtin_amdgcn_rcpf)
          float sc = s * __builtin_amdgcn_rsqf(s + 1e-7f) *
                     __builtin_amdgcn_rcpf(1.0f + s);
#else
          float sc = s / ((1.0f + s) * sqrtf(s + 1e-7f));
#endif
          opj[n2 * 16] = u * sc;       // imm offsets 0/64/128/192 dwords
        }
      }
    }
  }
}

// ============================================================
extern "C" void kernel_launch(void* const* d_in, const int* in_sizes, int n_in,
                              void* d_out, int out_size, void* d_ws, size_t ws_size,
                              hipStream_t stream) {
  const float* ximg = (const float*)d_in[0];
  const float* xcapt = (const float*)d_in[1];
  const float* xdct = (const float*)d_in[2];
  const float* Wi = (const float*)d_in[3];
  const float* bi = (const float*)d_in[4];
  const float* Wc = (const float*)d_in[5];
  const float* bc = (const float*)d_in[6];
  const float* Wd = (const float*)d_in[7];
  const float* bd = (const float*)d_in[8];

  uintx4* Bprep = (uintx4*)d_ws;                           // 2.25 MiB
  float* biasPrep = (float*)((char*)d_ws + 2304 * 1024);   // 6 KiB

  hipLaunchKernelGGL(prep_w, dim3(576), dim3(256), 0, stream,
                     Wi, Wc, Wd, bi, bc, bd, Bprep, biasPrep);
  hipLaunchKernelGGL(caps_fused, dim3(1536), dim3(1024), 0, stream,
                     ximg, xcapt, xdct, (const uintx4*)Bprep, biasPrep,
                     (float*)d_out);
}

// Round 19
// 79.863 us; speedup vs baseline: 1.3356x; 1.3356x over previous
//
#include <hip/hip_runtime.h>

// ---------- types ----------
typedef __attribute__((ext_vector_type(8))) short short8;     // 8 bf16 (4 VGPRs)
typedef __attribute__((ext_vector_type(4))) float floatx4;    // MFMA C/D
typedef __attribute__((ext_vector_type(4))) unsigned int uintx4;

// ---------- fp32 -> packed bf16x2 (RNE) ----------
#if __has_builtin(__builtin_amdgcn_cvt_pk_bf16_f32)
typedef __attribute__((ext_vector_type(2))) __bf16 bf16x2;
__device__ __forceinline__ unsigned int pk_bf16(float a, float b) {
  bf16x2 v = __builtin_amdgcn_cvt_pk_bf16_f32(a, b);
  return __builtin_bit_cast(unsigned int, v);
}
#else
__device__ __forceinline__ unsigned int bf16_1(float f) {
  unsigned int u = __builtin_bit_cast(unsigned int, f);
  return (u + 0x7fffu + ((u >> 16) & 1u)) >> 16;
}
__device__ __forceinline__ unsigned int pk_bf16(float a, float b) {
  return bf16_1(a) | (bf16_1(b) << 16);
}
#endif

// Fragment conventions (verified rounds 0-18, absmax 3.9e-3):
//   A-frag (16x16x32): lane(ln,quad) holds A[m=ln][k=quad*8+j], j=0..7
//   B-frag:            lane(ln,quad) holds B[n=ln][k=quad*8+j]  (B[k][n]=W[c][r][k], n=r*8+c)
//   C/D:               col=ln, row=quad*4+reg
// Bprep frag id: Fb = ((mod*8 + h)*24 + ks)*4 + nt, n16 = h*4+nt; frag = 64 lanes x 16B.
//
// FINAL LEDGER (19 rounds, all single-variable unless noted):
// * STORE GEOMETRY LOAD-BEARING: 16 consecutive dwords per 16-lane group
//   x 4 rows/instr = 1.0x writes. Anything else measured 1.5-3.0x.
// * NT STORES: 3x writes (r3). NT LOADS: kill X's L3 residency (r15).
// * PERMUTED-B + direct stores: silent transpose (r6).
// * REG-SPILL SIGNATURE: WRITE balloon + 2.4x dur (r7).
// * B-TRAFFIC HALVING (64-row tiles, r9): clean test, duration ROSE ->
//   B bandwidth (L2 or L3) is NOT binding.
// * OCCUPANCY 43->76% (r10): null. PREFETCH 2->3 deep (r11): null.
// * 64x256 COL-SPLIT (r12): X HBM doubles; L3 does not absorb.
// * K-STAGGER (r13): null -> no convoying.
// * VALU DIET (r14): VALUBusy 29->19, duration null -> not issue-bound.
// * CONFIRMED MECHANISM (r15, NT isolation): X streaming evicts B from
//   per-XCD L2 -> B served from L3, ~23 us profiled cost. Instruments:
//   NT couples L2+L3 (bench net loss), SC1 null (r16), register-resident
//   B -> 1 blk/CU serial-stage +15 us (r17), LDS-resident B needs >=112 KB
//   -> 1 blk/CU +25 us (r18; also r18's K-split did NOT reduce block B
//   traffic: 16 waves x 48 KB == 8 x 96 KB).
// * STRUCTURAL FLOOR ARGUMENT: hiding ~500 cy of B-service latency at
//   32 KB/K-step needs ~200 KB in flight per block; registers cap at
//   12 KB/wave (spill), LDS caps at 160 KB (1 blk/CU tax ~25 us), TLP
//   beyond ~14 waves/CU measured null. Every decomposition's tax >= gain.
//   Floor ~= 40 us streaming + B-service stalls ~= 80 us. This kernel
//   (81.4 us) is the session best; restored after r17/r18 regressions.

// ============================================================
// Prepass W: [8][64][768] fp32 -> bf16 B-fragments; bias permuted to n-order.
// ============================================================
__global__ __launch_bounds__(256) void prep_w(
    const float* __restrict__ Wi, const float* __restrict__ Wc, const float* __restrict__ Wd,
    const float* __restrict__ bi, const float* __restrict__ bc, const float* __restrict__ bd,
    uintx4* __restrict__ Bprep, float* __restrict__ biasPrep) {
  const int t = blockIdx.x * 256 + threadIdx.x;  // 0 .. 147455
  const int l = t & 63;
  const int frag = t >> 6;             // 0 .. 2303
  const int nt = frag & 3;
  const int q = frag >> 2;
  const int ks = q % 24;
  const int q2 = q / 24;
  const int h = q2 & 7;
  const int mod = q2 >> 3;
  const int n16 = h * 4 + nt;
  const float* __restrict__ W = (mod == 0) ? Wi : ((mod == 1) ? Wc : Wd);

  const int n = n16 * 16 + (l & 15);
  const int r = n >> 3;
  const int c = n & 7;
  const int i0 = ks * 32 + (l >> 4) * 8;
  const float* src = W + (size_t)(c * 64 + r) * 768 + i0;
  floatx4 f0 = *(const floatx4*)(src);
  floatx4 f1 = *(const floatx4*)(src + 4);
  uintx4 p;
  p.x = pk_bf16(f0.x, f0.y);
  p.y = pk_bf16(f0.z, f0.w);
  p.z = pk_bf16(f1.x, f1.y);
  p.w = pk_bf16(f1.z, f1.w);
  Bprep[(size_t)frag * 64 + l] = p;

  if (t < 1536) {
    const int m2 = t >> 9;
    const int nn = t & 511;
    const float* bb = (m2 == 0) ? bi : ((m2 == 1) ? bc : bd);
    biasPrep[t] = bb[(nn & 7) * 64 + (nn >> 3)];
  }
}

// ============================================================
// Fused GEMM + squash — SESSION BEST (round 11, 81.43 us), restored.
//   Block: 512 thr / 8 waves; wave owns 32x64 (acc[2][4] = 32 AGPR).
//   A (32x768) staged once as bf16 frags in 48 KB LDS (slot-XOR), one
//   barrier, 24-step K-loop as 7x3 pipelined + 3-step drain, 3-deep
//   register prefetch (a0/a1/a2, b0/b1/b2), ~100 of 128-reg cap.
//   Epilogue: shuffle-squash + fast rsq/rcp + proven 1.0x store geometry.
//   Grid 1536 = 3 mods x 512 m-tiles (XCD swizzle 8x192).
// ============================================================
#define LOADA(aa, kk)                                                        \
  {                                                                          \
    _Pragma("unroll") for (int mt = 0; mt < 2; ++mt)                         \
        aa[mt] = Afr[((kk) * 2 + mt) * 64 +                                  \
                     ((ln ^ (((kk) * 4 + quad) & 15)) + (quad << 4))];       \
  }

#define LOADB(bb, kk)                                                        \
  {                                                                          \
    _Pragma("unroll") for (int n2 = 0; n2 < 4; ++n2)                         \
        bb[n2] = bbase[(size_t)((kk) * 4 + n2) * 64];                        \
  }

#define COMP(aa, bb)                                                     \
  {                                                                      \
    _Pragma("unroll") for (int mt = 0; mt < 2; ++mt)                     \
    {                                                                    \
      short8 af = __builtin_bit_cast(short8, aa[mt]);                    \
      _Pragma("unroll") for (int n2 = 0; n2 < 4; ++n2)                   \
          acc[mt][n2] = __builtin_amdgcn_mfma_f32_16x16x32_bf16(         \
              af, __builtin_bit_cast(short8, bb[n2]), acc[mt][n2], 0, 0, \
              0);                                                        \
    }                                                                    \
  }

__global__ __launch_bounds__(512, 4) void caps_fused(
    const float* __restrict__ x0, const float* __restrict__ x1, const float* __restrict__ x2,
    const uintx4* __restrict__ Bprep, const float* __restrict__ biasPrep,
    float* __restrict__ out) {
  __shared__ unsigned long long As64[48 * 128];  // 48 frags x 64 slots x 16 B

  const int tid = threadIdx.x;
  // XCD-chunk swizzle: 1536 = 8 XCDs x 192 contiguous blocks (bijective).
  const int bx0 = blockIdx.x;
  const int bx = (bx0 & 7) * 192 + (bx0 >> 3);
  const int mod = bx >> 9;           // 1536 = 3 x 512
  const int bm = bx & 511;           // m-tile (32 rows)
  const float* __restrict__ X = (mod == 0) ? x0 : ((mod == 1) ? x1 : x2);

  // ---- one-shot staging: 32 rows x 768 cols fp32, coalesced, 512 thr ----
  const float* src = X + (size_t)bm * 32 * 768;
#pragma unroll
  for (int i = 0; i < 12; ++i) {
    const int idx = i * 2048 + tid * 4;          // flat float index in tile
    floatx4 f = *(const floatx4*)(src + idx);
    const int m = (unsigned)idx / 768u;
    const int k = idx - m * 768;
    const int ks = k >> 5;
    const int kk = k & 31;
    const int qk = kk >> 3;                      // quad of k
    const int jh = (kk >> 2) & 1;                // which 8-byte half
    const int mt = m >> 4;
    const int lnn = m & 15;
    const int p = (ks * 4 + qk) & 15;            // slot-XOR spread
    const int slot = (lnn ^ p) + (qk << 4);
    unsigned long long w =
        ((unsigned long long)pk_bf16(f.z, f.w) << 32) | pk_bf16(f.x, f.y);
    As64[(((ks * 2 + mt) * 64 + slot) << 1) + jh] = w;
  }
  __syncthreads();  // the ONLY barrier

  const int lane = tid & 63;
  const int ln = lane & 15;
  const int quad = lane >> 4;
  const int wv = tid >> 6;  // wave id 0..7 == h: n16-range wv*4 .. wv*4+3

  const uintx4* Afr = (const uintx4*)As64;
  const uintx4* bbase = Bprep + (size_t)(mod * 8 + wv) * (96 * 64) + lane;

  floatx4 acc[2][4] = {};
  uintx4 a0[2], a1[2], a2[2], b0[4], b1[4], b2[4];

  LOADA(a0, 0); LOADB(b0, 0);
  LOADA(a1, 1); LOADB(b1, 1);
  LOADA(a2, 2); LOADB(b2, 2);
#pragma unroll 1
  for (int it = 0; it < 7; ++it) {
    const int s = 3 * it;
    COMP(a0, b0);
    LOADA(a0, s + 3); LOADB(b0, s + 3);
    COMP(a1, b1);
    LOADA(a1, s + 4); LOADB(b1, s + 4);
    COMP(a2, b2);
    LOADA(a2, s + 5); LOADB(b2, s + 5);
  }
  COMP(a0, b0);   // step 21
  COMP(a1, b1);   // step 22
  COMP(a2, b2);   // step 23

  // ---- epilogue: bias + squash (8 capsule lanes share s) + store ----
  const int col0 = mod * 512 + wv * 64 + ln;
  float bias[4];
#pragma unroll
  for (int n2 = 0; n2 < 4; ++n2) bias[n2] = biasPrep[col0 + n2 * 16];

#pragma unroll
  for (int mt = 0; mt < 2; ++mt) {
    const size_t rbase = (size_t)(bm * 32 + mt * 16 + quad * 4) * 1536;
#pragma unroll
    for (int n2 = 0; n2 < 4; ++n2) {
      float* op = out + rbase + col0 + n2 * 16;
#pragma unroll
      for (int jj = 0; jj < 4; ++jj) {
        float u = acc[mt][n2][jj] + bias[n2];
        float s = u * u;
        s += __shfl_xor(s, 1);
        s += __shfl_xor(s, 2);
        s += __shfl_xor(s, 4);
#if __has_builtin(__builtin_amdgcn_rsqf) && __has_builtin(__builtin_amdgcn_rcpf)
        float sc = s * __builtin_amdgcn_rsqf(s + 1e-7f) *
                   __builtin_amdgcn_rcpf(1.0f + s);
#else
        float sc = s / ((1.0f + s) * sqrtf(s + 1e-7f));
#endif
        op[(size_t)jj * 1536] = u * sc;
      }
    }
  }
}

// ============================================================
extern "C" void kernel_launch(void* const* d_in, const int* in_sizes, int n_in,
                              void* d_out, int out_size, void* d_ws, size_t ws_size,
                              hipStream_t stream) {
  const float* ximg = (const float*)d_in[0];
  const float* xcapt = (const float*)d_in[1];
  const float* xdct = (const float*)d_in[2];
  const float* Wi = (const float*)d_in[3];
  const float* bi = (const float*)d_in[4];
  const float* Wc = (const float*)d_in[5];
  const float* bc = (const float*)d_in[6];
  const float* Wd = (const float*)d_in[7];
  const float* bd = (const float*)d_in[8];

  uintx4* Bprep = (uintx4*)d_ws;                           // 2.25 MiB
  float* biasPrep = (float*)((char*)d_ws + 2304 * 1024);   // 6 KiB

  hipLaunchKernelGGL(prep_w, dim3(576), dim3(256), 0, stream,
                     Wi, Wc, Wd, bi, bc, bd, Bprep, biasPrep);
  hipLaunchKernelGGL(caps_fused, dim3(1536), dim3(512), 0, stream,
                     ximg, xcapt, xdct, (const uintx4*)Bprep, biasPrep,
                     (float*)d_out);
}